// Round 9
// baseline (155.831 us; speedup 1.0000x reference)
//
#include <hip/hip_runtime.h>

typedef __bf16 bf16_t;
typedef __bf16 bf16x8 __attribute__((ext_vector_type(8)));
typedef __bf16 bf16x4 __attribute__((ext_vector_type(4)));
typedef __bf16 bf16x2 __attribute__((ext_vector_type(2)));
typedef float  f32x4  __attribute__((ext_vector_type(4)));
typedef float  f32x16 __attribute__((ext_vector_type(16)));
struct uint4_t { unsigned x, y, z, w; };

#define B_  4
#define L_  4096
#define D_  1024
#define HS  64
#define NQ  192
// scale * log2(e) = 0.125 * 1.4426950408889634
#define SCL2E 0.1803368801111204f
#define MFMA16 __builtin_amdgcn_mfma_f32_16x16x32_bf16
#define MFMA32 __builtin_amdgcn_mfma_f32_32x32x16_bf16

static __device__ __forceinline__ unsigned pk_bf16(float a, float b) {
    union { bf16x2 v; unsigned u; } x;
    x.v[0] = (bf16_t)a; x.v[1] = (bf16_t)b;
    return x.u;
}
// v_permlane32_swap_b32 x,y:  x[32:63] <- y[0:31];  y[0:31] <- x[32:63]
static __device__ __forceinline__ void swap32(unsigned& x, unsigned& y) {
    asm("v_permlane32_swap_b32 %0, %1" : "+v"(x), "+v"(y));
}

// ---------------------------------------------------------------------------
// Kernel 1: dtype detect + pack W into MFMA B-fragment order + build m01
// (bf16 0/1 attend-mask vector used for V-row zeroing and the denominator).
// flags[0]: mask kind 0=int32, 1=uint8, 2=float32;  flags[1]: fp32 io
// ---------------------------------------------------------------------------
__global__ __launch_bounds__(256) void pack_w_kernel(const void* __restrict__ Win,
                                                     const unsigned char* __restrict__ mask,
                                                     const unsigned short* __restrict__ xw,
                                                     bf16_t* __restrict__ Wtp,
                                                     int* __restrict__ flags,
                                                     bf16_t* __restrict__ m01) {
    __shared__ int c1, c23, cbad;
    int tid = threadIdx.x;
    if (tid == 0) { c1 = 0; c23 = 0; cbad = 0; }
    __syncthreads();
    uint4_t m[4];
#pragma unroll
    for (int i = 0; i < 4; ++i)
        m[i] = *(const uint4_t*)(mask + tid * 16 + i * 4096);
    int a = 0, bc = 0;
#pragma unroll
    for (int i = 0; i < 4; ++i) {
        const unsigned* w = (const unsigned*)&m[i];
#pragma unroll
        for (int j = 0; j < 4; ++j) {
            if (w[j] & 0x0000ff00u) a++;     // byte1 nonzero -> uint8 mask
            if (w[j] & 0xffff0000u) bc++;    // byte2/3 nonzero -> int32/fp32
        }
    }
    uint4_t xm = *(const uint4_t*)(xw + tid * 8);
    int bad = 0;
    const unsigned* xwv = (const unsigned*)&xm;
#pragma unroll
    for (int j = 0; j < 4; ++j)
#pragma unroll
        for (int h = 0; h < 2; ++h) {
            unsigned s = (xwv[j] >> (16 * h)) & 0xFFFFu;
            unsigned e = (s >> 7) & 0xFF;
            if (e > 150 || (e < 90 && e != 0)) bad++;
        }
    if (a)   atomicAdd(&c1, a);
    if (bc)  atomicAdd(&c23, bc);
    if (bad) atomicAdd(&cbad, bad);
    __syncthreads();
    int f32 = (cbad >= 64) ? 1 : 0;
    int kind = (c1 > 0) ? 1 : ((c23 > 0) ? 2 : 0);   // block-local consensus (same sample -> same answer)
    if (blockIdx.x == 0 && tid == 0) {
        flags[0] = kind;
        flags[1] = f32;
    }

    int idx = blockIdx.x * 256 + tid;

    // ---- m01: bf16 1.0 for attend, 0.0 for masked ----
    if (idx < B_ * L_) {
        bool mv;
        if (kind == 1)      mv = mask[idx] != 0;
        else if (kind == 2) mv = ((const float*)mask)[idx] != 0.0f;
        else                mv = ((const int*)mask)[idx] != 0;
        m01[idx] = (bf16_t)(mv ? 1.0f : 0.0f);
    }

    // ---- pack W (grid 96 x 256 = 24576 units exactly) ----
    int lane = idx & 63;
    int t    = (idx >> 6) & 3;
    int kc   = (idx >> 8) & 31;
    int ct   = idx >> 13;
    int n  = ct * 64 + t * 16 + (lane & 15);
    int k0 = kc * 32 + (lane >> 4) * 8;
    bf16x8 v;
#pragma unroll
    for (int j = 0; j < 8; ++j) {
        if (f32) v[j] = (bf16_t)(((const float*)Win)[(k0 + j) * NQ + n]);
        else     v[j] = ((const bf16_t*)Win)[(k0 + j) * NQ + n];
    }
    *(bf16x8*)(Wtp + (size_t)idx * 8) = v;
}

// ---------------------------------------------------------------------------
// Kernel 2: QKV GEMM. Block = 32 rows x 192 cols, grid 512. (unchanged)
//   Q: row-major, pre-scaled by scale*log2e in fp32 before bf16 rounding.
//   K: fragment blob  Kp[b][t64][stile][chunk][lane=hi*32+k31][8]
//   V: fragment blob  Vp[b][t64][dtile][chunk][lane=hi*32+d31][8], masked rows zeroed
// ---------------------------------------------------------------------------
__global__ __launch_bounds__(256, 2) void qkv_gemm_kernel(const void* __restrict__ xin,
                                                          const int* __restrict__ flags,
                                                          const bf16_t* __restrict__ Wtp,
                                                          const bf16_t* __restrict__ m01p,
                                                          bf16_t* __restrict__ Qb,
                                                          bf16_t* __restrict__ Kp,
                                                          bf16_t* __restrict__ Vp) {
    __shared__ __align__(16) bf16_t xs[32 * 520];    // 32.5 KB
    __shared__ __align__(16) bf16_t sqk[32 * 136];
    __shared__ __align__(16) bf16_t sv[64 * 40];

    int tid = threadIdx.x;
    int wave = tid >> 6, lane = tid & 63, quad = lane >> 4, l16 = lane & 15;
    int rg = wave & 1, ch = wave >> 1;
    int m0 = blockIdx.x * 32;
    int xf = flags[1];

    f32x4 acc[6] = {};
    bf16x8 Ba[6], Bb[6];

    auto stage = [&](int h) {
        bf16x8 tmp[8];
#pragma unroll
        for (int j = 0; j < 8; ++j) {
            int c = tid + j * 256;
            int row = c >> 6, off = (c & 63) * 8;
            if (xf) {
                const float* xp = (const float*)xin + (size_t)(m0 + row) * D_ + h * 512 + off;
                f32x4 lo = *(const f32x4*)xp, hi = *(const f32x4*)(xp + 4);
                tmp[j][0] = (bf16_t)lo[0]; tmp[j][1] = (bf16_t)lo[1];
                tmp[j][2] = (bf16_t)lo[2]; tmp[j][3] = (bf16_t)lo[3];
                tmp[j][4] = (bf16_t)hi[0]; tmp[j][5] = (bf16_t)hi[1];
                tmp[j][6] = (bf16_t)hi[2]; tmp[j][7] = (bf16_t)hi[3];
            } else {
                tmp[j] = *(const bf16x8*)((const bf16_t*)xin + (size_t)(m0 + row) * D_ + h * 512 + off);
            }
        }
#pragma unroll
        for (int j = 0; j < 8; ++j) {
            int c = tid + j * 256;
            int row = c >> 6, off = (c & 63) * 8;
            *(bf16x8*)&xs[row * 520 + off] = tmp[j];
        }
    };
    auto loadB6 = [&](int ks, bf16x8* Bv) {
#pragma unroll
        for (int i = 0; i < 6; ++i) {
            int st = ch * 6 + i, ct2 = st >> 2, tt = st & 3;
            Bv[i] = *(const bf16x8*)(Wtp + ((size_t)(ct2 * 32 + ks) * 4 + tt) * 512 + lane * 8);
        }
    };
    auto compute6 = [&](int ks, const bf16x8* Bv) {
        bf16x8 A = *(const bf16x8*)&xs[(rg * 16 + l16) * 520 + (ks & 15) * 32 + quad * 8];
#pragma unroll
        for (int i = 0; i < 6; ++i)
            acc[i] = MFMA16(A, Bv[i], acc[i], 0, 0, 0);
    };

    stage(0);
    loadB6(0, Ba);
    __syncthreads();
#pragma unroll
    for (int half = 0; half < 2; ++half) {
        int base = half * 16;
        for (int m = 0; m < 16; m += 2) {
            int ks = base + m;
            loadB6(ks + 1, Bb);
            compute6(ks, Ba);
            loadB6(ks + 2 <= 31 ? ks + 2 : 31, Ba);
            compute6(ks + 1, Bb);
        }
        if (half == 0) {
            __syncthreads();
            stage(1);
            __syncthreads();
        }
    }

    // Epilogue: stage to LDS (Q pre-scaled), then emit fragment-ordered blobs.
    int rowb = rg * 16 + quad * 4;
#pragma unroll
    for (int i = 0; i < 6; ++i) {
        int col = ch * 96 + i * 16 + l16;
#pragma unroll
        for (int r = 0; r < 4; ++r) {
            float av = acc[i][r];
            if (col < 64) av *= SCL2E;          // fold softmax scale into Q (fp32, pre-round)
            bf16_t hv = (bf16_t)av;
            if (col < 128) sqk[(rowb + r) * 136 + col] = hv;
            else           sv[(col - 128) * 40 + rowb + r] = hv;
        }
    }
    __syncthreads();

    int bb = m0 >> 12, l0 = m0 & 4095;
    int t64 = l0 >> 6, stile = (l0 >> 5) & 1, ctop = (l0 >> 4) & 2;
    // Q rows (coalesced 16B)
    {
        int row = tid >> 3, off = (tid & 7) * 8;
        bf16x8 v = *(const bf16x8*)&sqk[row * 136 + off];
        *(bf16x8*)(Qb + (size_t)(m0 + row) * HS + off) = v;
    }
    // K fragment blob: 256 x 16B
    {
        int chk = tid >> 6, ln = tid & 63;
        bf16x8 v = *(const bf16x8*)&sqk[(tid & 31) * 136 + 64 + chk * 16 + ((tid >> 5) & 1) * 8];
        *(bf16x8*)(Kp + (size_t)bb * (L_ * HS) +
                   ((((size_t)t64 * 2 + stile) * 4 + chk) * 64 + ln) * 8) = v;
    }
    // V fragment blob, masked rows zeroed: 256 x 16B
    {
        int dt = tid >> 7, chL = (tid >> 6) & 1, ln = tid & 63;
        int hi2 = (tid >> 5) & 1, d31 = tid & 31;
        bf16x8 v  = *(const bf16x8*)&sv[(dt * 32 + d31) * 40 + chL * 16 + hi2 * 8];
        bf16x8 mm = *(const bf16x8*)(m01p + (size_t)m0 + chL * 16 + hi2 * 8);
        bf16x8 o;
#pragma unroll
        for (int j = 0; j < 8; ++j) o[j] = (bf16_t)((float)v[j] * (float)mm[j]);
        *(bf16x8*)(Vp + (size_t)bb * (L_ * HS) +
                   ((((size_t)t64 * 2 + dt) * 4 + ctop + chL) * 64 + ln) * 8) = o;
    }
}

// ---------------------------------------------------------------------------
// Kernel 3: attention — all-register, DUAL-Q waves (64 q-rows/wave).
// Round-8 post-mortem: inner loop was L1-BANDWIDTH-bound — 8x 1KB loads
// (K4+V4) per wave-halftile serve only one 32q x 32k unit (~128 cyc L1
// service vs ~80 cyc MFMA). q is the amortization axis: two 32-q groups
// (A,B) share one K/V/M load set per halftile -> VMEM instr per unit work
// HALVES. A and B are independent chains (extra in-wave ILP compensates
// the TLP drop from bigger registers). Order: QK_A -> exp/PV_A -> QK_B
// (K still live) -> K-prefetch(t+1) -> exp/PV_B; one S live at a time.
// Grid 512 (2 blocks/CU, 8 waves/CU, 2/SIMD); VGPR ~200-220 under (256,2).
// ---------------------------------------------------------------------------
template<int NSPLIT>
__global__ __launch_bounds__(256, 2) void attn_kernel(const bf16_t* __restrict__ Qb,
                                                      const bf16_t* __restrict__ Kp,
                                                      const bf16_t* __restrict__ Vp,
                                                      const bf16_t* __restrict__ m01p,
                                                      const int* __restrict__ flags,
                                                      float* __restrict__ Opart,
                                                      float* __restrict__ lpart,
                                                      void* __restrict__ outv) {
    constexpr int KCH = L_ / NSPLIT;
    constexpr int NHT = KCH / 32;                     // 32-key half-tiles

    int tid = threadIdx.x, wave = tid >> 6, lane = tid & 63;
    int hi = lane >> 5, l31 = lane & 31;
    int grp = blockIdx.x % (B_ * NSPLIT);
    int qt  = blockIdx.x / (B_ * NSPLIT);
    int sp = grp / B_, b = grp % B_;
    int q0 = qt * 256 + wave * 64;                    // 64 q-rows per wave
    int hb = sp * NHT;

    const bf16_t* KpB = Kp + (size_t)b * (L_ * HS);
    const bf16_t* VpB = Vp + (size_t)b * (L_ * HS);
    const bf16_t* mB  = m01p + (size_t)b * L_ + sp * KCH;

    // Q as MFMA32 B-frag for both groups: B[col=q=l31][k_hs=hi*8+j], 4 chunks.
    bf16x8 QfA[4], QfB[4];
    {
        const bf16_t* qa = Qb + (size_t)(b * L_ + q0 + l31) * HS + hi * 8;
        const bf16_t* qb = Qb + (size_t)(b * L_ + q0 + 32 + l31) * HS + hi * 8;
#pragma unroll
        for (int c = 0; c < 4; ++c) {
            QfA[c] = *(const bf16x8*)(qa + c * 16);
            QfB[c] = *(const bf16x8*)(qb + c * 16);
        }
    }

    f32x16 O0A = {}, O1A = {}, denA = {};
    f32x16 O0B = {}, O1B = {}, denB = {};

    auto loadK = [&](bf16x8* Kf, int t) {
        const bf16_t* kt = KpB + (size_t)(hb + t) * 2048;
#pragma unroll
        for (int c = 0; c < 4; ++c)
            Kf[c] = *(const bf16x8*)(kt + ((size_t)c * 64 + lane) * 8);
    };

    bf16x8 Kfr[4];
    loadK(Kfr, 0);                       // cold start: one exposed latency

    for (int t = 0; t < NHT; ++t) {
        int ht = hb + t;
        int t64 = ht >> 1, stile = ht & 1;
        const bf16_t* vt = VpB + (size_t)t64 * 4096;
        const bf16_t* mt = mB + t * 32;

        // V + m01 for THIS tile (shared by PV_A and PV_B), issued before QK.
        bf16x8 V0[2], V1[2], Mf[2];
#pragma unroll
        for (int cc = 0; cc < 2; ++cc) {
            int chk = stile * 2 + cc;
            V0[cc] = *(const bf16x8*)(vt + (size_t)(0 * 4 + chk) * 512 + lane * 8);
            V1[cc] = *(const bf16x8*)(vt + (size_t)(1 * 4 + chk) * 512 + lane * 8);
            Mf[cc] = *(const bf16x8*)(mt + cc * 16 + hi * 8);   // broadcast 16B
        }

        // ---------------- group A ----------------
        {
            f32x16 S = {};
            __builtin_amdgcn_s_setprio(1);
#pragma unroll
            for (int c = 0; c < 4; ++c)
                S = MFMA32(Kfr[c], QfA[c], S, 0, 0, 0);   // S[k][q], lane q=l31
            __builtin_amdgcn_s_setprio(0);
#pragma unroll
            for (int r = 0; r < 16; ++r) S[r] = exp2f(S[r]);
#pragma unroll
            for (int cc = 0; cc < 2; ++cc) {
                unsigned w0 = pk_bf16(S[cc * 8 + 0], S[cc * 8 + 1]);
                unsigned w1 = pk_bf16(S[cc * 8 + 2], S[cc * 8 + 3]);
                unsigned w2 = pk_bf16(S[cc * 8 + 4], S[cc * 8 + 5]);
                unsigned w3 = pk_bf16(S[cc * 8 + 6], S[cc * 8 + 7]);
                swap32(w0, w2);
                swap32(w1, w3);
                union { unsigned u[4]; bf16x8 v; } P;
                P.u[0] = w0; P.u[1] = w1; P.u[2] = w2; P.u[3] = w3;
                __builtin_amdgcn_s_setprio(1);
                O0A  = MFMA32(P.v, V0[cc], O0A, 0, 0, 0);
                O1A  = MFMA32(P.v, V1[cc], O1A, 0, 0, 0);
                denA = MFMA32(P.v, Mf[cc], denA, 0, 0, 0);
                __builtin_amdgcn_s_setprio(0);
            }
        }

        // ---------------- group B ----------------
        {
            f32x16 S = {};
            __builtin_amdgcn_s_setprio(1);
#pragma unroll
            for (int c = 0; c < 4; ++c)
                S = MFMA32(Kfr[c], QfB[c], S, 0, 0, 0);   // last use of Kfr(t)
            __builtin_amdgcn_s_setprio(0);
            // K prefetch for t+1: after the final Kfr read; in flight under
            // exp/pack/PV_B (~300 cyc) — full latency cover, no extra regs.
            if (t + 1 < NHT) loadK(Kfr, t + 1);
#pragma unroll
            for (int r = 0; r < 16; ++r) S[r] = exp2f(S[r]);
#pragma unroll
            for (int cc = 0; cc < 2; ++cc) {
                unsigned w0 = pk_bf16(S[cc * 8 + 0], S[cc * 8 + 1]);
                unsigned w1 = pk_bf16(S[cc * 8 + 2], S[cc * 8 + 3]);
                unsigned w2 = pk_bf16(S[cc * 8 + 4], S[cc * 8 + 5]);
                unsigned w3 = pk_bf16(S[cc * 8 + 6], S[cc * 8 + 7]);
                swap32(w0, w2);
                swap32(w1, w3);
                union { unsigned u[4]; bf16x8 v; } P;
                P.u[0] = w0; P.u[1] = w1; P.u[2] = w2; P.u[3] = w3;
                __builtin_amdgcn_s_setprio(1);
                O0B  = MFMA32(P.v, V0[cc], O0B, 0, 0, 0);
                O1B  = MFMA32(P.v, V1[cc], O1B, 0, 0, 0);
                denB = MFMA32(P.v, Mf[cc], denB, 0, 0, 0);
                __builtin_amdgcn_s_setprio(0);
            }
        }
    }

    // Epilogue for both groups. O layout: col=l31=d; regs = q rows.
    if (NSPLIT == 1) {
        int of32 = flags[1];
#pragma unroll
        for (int g = 0; g < 2; ++g) {
            const f32x16& O0 = g ? O0B : O0A;
            const f32x16& O1 = g ? O1B : O1A;
            const f32x16& dn = g ? denB : denA;
#pragma unroll
            for (int r = 0; r < 16; ++r) {
                int qr = (r & 3) + 8 * (r >> 2) + 4 * hi;
                float inv = 1.0f / dn[r];
                size_t base = (size_t)(b * L_ + q0 + g * 32 + qr) * HS;
                if (of32) {
                    float* op = (float*)outv + base;
                    op[l31]      = O0[r] * inv;
                    op[32 + l31] = O1[r] * inv;
                } else {
                    bf16_t* op = (bf16_t*)outv + base;
                    op[l31]      = (bf16_t)(O0[r] * inv);
                    op[32 + l31] = (bf16_t)(O1[r] * inv);
                }
            }
        }
    } else {
#pragma unroll
        for (int g = 0; g < 2; ++g) {
            const f32x16& O0 = g ? O0B : O0A;
            const f32x16& O1 = g ? O1B : O1A;
            const f32x16& dn = g ? denB : denA;
            float* op = Opart + (size_t)sp * (B_ * L_ * HS)
                              + (size_t)(b * L_ + q0 + g * 32) * HS + l31;
#pragma unroll
            for (int r = 0; r < 16; ++r) {
                int qr = (r & 3) + 8 * (r >> 2) + 4 * hi;
                op[(size_t)qr * HS]      = O0[r];
                op[(size_t)qr * HS + 32] = O1[r];
            }
            if (l31 == 0) {
                float* lp = lpart + (size_t)sp * (B_ * L_) + b * L_ + q0 + g * 32;
#pragma unroll
                for (int r = 0; r < 16; ++r)
                    lp[(r & 3) + 8 * (r >> 2) + 4 * hi] = dn[r];
            }
        }
    }
}

// ---------------------------------------------------------------------------
// Kernel 4: combine split-K partials, f32x4-vectorized.
// ---------------------------------------------------------------------------
__global__ __launch_bounds__(256) void reduce_kernel(const float* __restrict__ Opart,
                                                     const float* __restrict__ lpart,
                                                     const int* __restrict__ flags,
                                                     void* __restrict__ outv,
                                                     int nsplit) {
    int i4 = (blockIdx.x * 256 + threadIdx.x) * 4;   // over B_*L_*HS
    int row = i4 >> 6;                                // b*L_ + l
    f32x4 acc = {};
    float lsum = 0.f;
    for (int s = 0; s < nsplit; ++s) {
        acc  += *(const f32x4*)&Opart[(size_t)s * (B_ * L_ * HS) + i4];
        lsum += lpart[(size_t)s * (B_ * L_) + row];
    }
    float inv = 1.0f / lsum;
    if (flags[1]) {
        f32x4 r = { acc[0] * inv, acc[1] * inv, acc[2] * inv, acc[3] * inv };
        *(f32x4*)&((float*)outv)[i4] = r;
    } else {
        bf16x4 r;
#pragma unroll
        for (int j = 0; j < 4; ++j) r[j] = (bf16_t)(acc[j] * inv);
        *(bf16x4*)&((bf16_t*)outv)[i4] = r;
    }
}

// ---------------------------------------------------------------------------
extern "C" void kernel_launch(void* const* d_in, const int* in_sizes, int n_in,
                              void* d_out, int out_size, void* d_ws, size_t ws_size,
                              hipStream_t stream) {
    (void)in_sizes; (void)n_in; (void)out_size;
    const void* x    = d_in[0];
    const void* mask = d_in[1];
    const void* W    = d_in[2];

    char* ws = (char*)d_ws;
    bf16_t* Qb    = (bf16_t*)(ws);                              // 2 MB
    bf16_t* Kp    = (bf16_t*)(ws + (2u << 20));                 // 2 MB (fragment blob)
    bf16_t* Vp    = (bf16_t*)(ws + (4u << 20));                 // 2 MB (fragment blob)
    bf16_t* Wtp   = (bf16_t*)(ws + (6u << 20));                 // 384 KB
    int*    flags = (int*)   (ws + (6u << 20) + (512u << 10));  // 4 KB
    bf16_t* m01p  = (bf16_t*)(ws + (6u << 20) + (516u << 10));  // 32 KB
    float*  Opart = (float*) (ws + (7u << 20));                 // nsplit * 4 MB

    auto need = [](int ns) -> size_t {
        return (7u << 20) + (size_t)ns * (B_ * L_ * HS * 4)
                          + (size_t)ns * (B_ * L_ * 4) + 4096;
    };
    int nsplit = (ws_size >= need(8)) ? 8 : (ws_size >= need(4)) ? 4 : 1;
    float* lpart = (float*)(ws + (7u << 20) + (size_t)nsplit * (B_ * L_ * HS * 4));

    pack_w_kernel<<<96, 256, 0, stream>>>(W, (const unsigned char*)mask,
                                          (const unsigned short*)x, Wtp, flags, m01p);
    qkv_gemm_kernel<<<512, 256, 0, stream>>>(x, flags, Wtp, m01p, Qb, Kp, Vp);
    if (nsplit == 8) {
        attn_kernel<8><<<16 * B_ * 8, 256, 0, stream>>>(Qb, Kp, Vp, m01p, flags,
                                                        Opart, lpart, d_out);
        reduce_kernel<<<(B_ * L_ * HS) / 1024, 256, 0, stream>>>(Opart, lpart, flags,
                                                                 d_out, 8);
    } else if (nsplit == 4) {
        attn_kernel<4><<<16 * B_ * 4, 256, 0, stream>>>(Qb, Kp, Vp, m01p, flags,
                                                        Opart, lpart, d_out);
        reduce_kernel<<<(B_ * L_ * HS) / 1024, 256, 0, stream>>>(Opart, lpart, flags,
                                                                 d_out, 4);
    } else {
        attn_kernel<1><<<16 * B_, 256, 0, stream>>>(Qb, Kp, Vp, m01p, flags,
                                                    Opart, lpart, d_out);
    }
}

// Round 10
// 152.563 us; speedup vs baseline: 1.0214x; 1.0214x over previous
//
#include <hip/hip_runtime.h>

typedef __bf16 bf16_t;
typedef __bf16 bf16x8 __attribute__((ext_vector_type(8)));
typedef __bf16 bf16x4 __attribute__((ext_vector_type(4)));
typedef __bf16 bf16x2 __attribute__((ext_vector_type(2)));
typedef float  f32x4  __attribute__((ext_vector_type(4)));
typedef float  f32x16 __attribute__((ext_vector_type(16)));
struct uint4_t { unsigned x, y, z, w; };

#define B_  4
#define L_  4096
#define D_  1024
#define HS  64
#define NQ  192
// scale * log2(e) = 0.125 * 1.4426950408889634
#define SCL2E 0.1803368801111204f
#define MFMA16 __builtin_amdgcn_mfma_f32_16x16x32_bf16
#define MFMA32 __builtin_amdgcn_mfma_f32_32x32x16_bf16

static __device__ __forceinline__ unsigned pk_bf16(float a, float b) {
    union { bf16x2 v; unsigned u; } x;
    x.v[0] = (bf16_t)a; x.v[1] = (bf16_t)b;
    return x.u;
}
// v_permlane32_swap_b32 x,y:  x[32:63] <- y[0:31];  y[0:31] <- x[32:63]
static __device__ __forceinline__ void swap32(unsigned& x, unsigned& y) {
    asm("v_permlane32_swap_b32 %0, %1" : "+v"(x), "+v"(y));
}

// ---------------------------------------------------------------------------
// Kernel 1: dtype detect + pack W into MFMA B-fragment order + build m01
// (bf16 0/1 attend-mask vector used for V-row zeroing and the denominator).
// flags[0]: mask kind 0=int32, 1=uint8, 2=float32;  flags[1]: fp32 io
// ---------------------------------------------------------------------------
__global__ __launch_bounds__(256) void pack_w_kernel(const void* __restrict__ Win,
                                                     const unsigned char* __restrict__ mask,
                                                     const unsigned short* __restrict__ xw,
                                                     bf16_t* __restrict__ Wtp,
                                                     int* __restrict__ flags,
                                                     bf16_t* __restrict__ m01) {
    __shared__ int c1, c23, cbad;
    int tid = threadIdx.x;
    if (tid == 0) { c1 = 0; c23 = 0; cbad = 0; }
    __syncthreads();
    uint4_t m[4];
#pragma unroll
    for (int i = 0; i < 4; ++i)
        m[i] = *(const uint4_t*)(mask + tid * 16 + i * 4096);
    int a = 0, bc = 0;
#pragma unroll
    for (int i = 0; i < 4; ++i) {
        const unsigned* w = (const unsigned*)&m[i];
#pragma unroll
        for (int j = 0; j < 4; ++j) {
            if (w[j] & 0x0000ff00u) a++;     // byte1 nonzero -> uint8 mask
            if (w[j] & 0xffff0000u) bc++;    // byte2/3 nonzero -> int32/fp32
        }
    }
    uint4_t xm = *(const uint4_t*)(xw + tid * 8);
    int bad = 0;
    const unsigned* xwv = (const unsigned*)&xm;
#pragma unroll
    for (int j = 0; j < 4; ++j)
#pragma unroll
        for (int h = 0; h < 2; ++h) {
            unsigned s = (xwv[j] >> (16 * h)) & 0xFFFFu;
            unsigned e = (s >> 7) & 0xFF;
            if (e > 150 || (e < 90 && e != 0)) bad++;
        }
    if (a)   atomicAdd(&c1, a);
    if (bc)  atomicAdd(&c23, bc);
    if (bad) atomicAdd(&cbad, bad);
    __syncthreads();
    int f32 = (cbad >= 64) ? 1 : 0;
    int kind = (c1 > 0) ? 1 : ((c23 > 0) ? 2 : 0);   // block-local consensus (same sample -> same answer)
    if (blockIdx.x == 0 && tid == 0) {
        flags[0] = kind;
        flags[1] = f32;
    }

    int idx = blockIdx.x * 256 + tid;

    // ---- m01: bf16 1.0 for attend, 0.0 for masked ----
    if (idx < B_ * L_) {
        bool mv;
        if (kind == 1)      mv = mask[idx] != 0;
        else if (kind == 2) mv = ((const float*)mask)[idx] != 0.0f;
        else                mv = ((const int*)mask)[idx] != 0;
        m01[idx] = (bf16_t)(mv ? 1.0f : 0.0f);
    }

    // ---- pack W (grid 96 x 256 = 24576 units exactly) ----
    int lane = idx & 63;
    int t    = (idx >> 6) & 3;
    int kc   = (idx >> 8) & 31;
    int ct   = idx >> 13;
    int n  = ct * 64 + t * 16 + (lane & 15);
    int k0 = kc * 32 + (lane >> 4) * 8;
    bf16x8 v;
#pragma unroll
    for (int j = 0; j < 8; ++j) {
        if (f32) v[j] = (bf16_t)(((const float*)Win)[(k0 + j) * NQ + n]);
        else     v[j] = ((const bf16_t*)Win)[(k0 + j) * NQ + n];
    }
    *(bf16x8*)(Wtp + (size_t)idx * 8) = v;
}

// ---------------------------------------------------------------------------
// Kernel 2: QKV GEMM. Block = 32 rows x 192 cols, grid 512.
// RESTRUCTURED WAVE MAPPING (round 10): each wave owns a 48-col slice x all
// 32 rows (ch = wave, rg inner loop) instead of 96 cols x 16 rows. The old
// pairing had waves 0/1 and 2/3 loading IDENTICAL B-fragment sets: Wtp L2
// traffic was 2x (768 KB/block), and the inner loop issued 6 VMEM loads per
// 6 MFMA16 (~96 cyc L1 vs ~29 cyc matrix). Now: 3 B-loads + 2 A-LDS-reads
// per 6 MFMA; each B-fragment read once per block (384 KB). Same tile,
// staging, barriers; epilogue remapped. VGPR drops (Ba/Bb 48->24).
//   Q: row-major, pre-scaled by scale*log2e in fp32 before bf16 rounding.
//   K: fragment blob  Kp[b][t64][stile][chunk][lane=hi*32+k31][8]
//   V: fragment blob  Vp[b][t64][dtile][chunk][lane=hi*32+d31][8], masked rows zeroed
// ---------------------------------------------------------------------------
__global__ __launch_bounds__(256, 2) void qkv_gemm_kernel(const void* __restrict__ xin,
                                                          const int* __restrict__ flags,
                                                          const bf16_t* __restrict__ Wtp,
                                                          const bf16_t* __restrict__ m01p,
                                                          bf16_t* __restrict__ Qb,
                                                          bf16_t* __restrict__ Kp,
                                                          bf16_t* __restrict__ Vp) {
    __shared__ __align__(16) bf16_t xs[32 * 520];    // 32.5 KB
    __shared__ __align__(16) bf16_t sqk[32 * 136];
    __shared__ __align__(16) bf16_t sv[64 * 40];

    int tid = threadIdx.x;
    int wave = tid >> 6, lane = tid & 63, quad = lane >> 4, l16 = lane & 15;
    int ch = wave;                        // 48-col slice per wave
    int m0 = blockIdx.x * 32;
    int xf = flags[1];

    f32x4 acc[2][3] = {};
    bf16x8 Ba[3], Bb[3];

    auto stage = [&](int h) {
        bf16x8 tmp[8];
#pragma unroll
        for (int j = 0; j < 8; ++j) {
            int c = tid + j * 256;
            int row = c >> 6, off = (c & 63) * 8;
            if (xf) {
                const float* xp = (const float*)xin + (size_t)(m0 + row) * D_ + h * 512 + off;
                f32x4 lo = *(const f32x4*)xp, hi = *(const f32x4*)(xp + 4);
                tmp[j][0] = (bf16_t)lo[0]; tmp[j][1] = (bf16_t)lo[1];
                tmp[j][2] = (bf16_t)lo[2]; tmp[j][3] = (bf16_t)lo[3];
                tmp[j][4] = (bf16_t)hi[0]; tmp[j][5] = (bf16_t)hi[1];
                tmp[j][6] = (bf16_t)hi[2]; tmp[j][7] = (bf16_t)hi[3];
            } else {
                tmp[j] = *(const bf16x8*)((const bf16_t*)xin + (size_t)(m0 + row) * D_ + h * 512 + off);
            }
        }
#pragma unroll
        for (int j = 0; j < 8; ++j) {
            int c = tid + j * 256;
            int row = c >> 6, off = (c & 63) * 8;
            *(bf16x8*)&xs[row * 520 + off] = tmp[j];
        }
    };
    auto loadB3 = [&](int ks, bf16x8* Bv) {
#pragma unroll
        for (int i = 0; i < 3; ++i) {
            int st = ch * 3 + i, ct2 = st >> 2, tt = st & 3;
            Bv[i] = *(const bf16x8*)(Wtp + ((size_t)(ct2 * 32 + ks) * 4 + tt) * 512 + lane * 8);
        }
    };
    auto compute3 = [&](int ks, const bf16x8* Bv) {
#pragma unroll
        for (int rg = 0; rg < 2; ++rg) {
            bf16x8 A = *(const bf16x8*)&xs[(rg * 16 + l16) * 520 + (ks & 15) * 32 + quad * 8];
#pragma unroll
            for (int i = 0; i < 3; ++i)
                acc[rg][i] = MFMA16(A, Bv[i], acc[rg][i], 0, 0, 0);
        }
    };

    stage(0);
    loadB3(0, Ba);
    __syncthreads();
#pragma unroll
    for (int half = 0; half < 2; ++half) {
        int base = half * 16;
        for (int m = 0; m < 16; m += 2) {
            int ks = base + m;
            loadB3(ks + 1, Bb);
            compute3(ks, Ba);
            loadB3(ks + 2 <= 31 ? ks + 2 : 31, Ba);
            compute3(ks + 1, Bb);
        }
        if (half == 0) {
            __syncthreads();
            stage(1);
            __syncthreads();
        }
    }

    // Epilogue: stage to LDS (Q pre-scaled), then emit fragment-ordered blobs.
#pragma unroll
    for (int rg = 0; rg < 2; ++rg) {
        int rowb = rg * 16 + quad * 4;
#pragma unroll
        for (int i = 0; i < 3; ++i) {
            int col = ch * 48 + i * 16 + l16;
#pragma unroll
            for (int r = 0; r < 4; ++r) {
                float av = acc[rg][i][r];
                if (col < 64) av *= SCL2E;      // fold softmax scale into Q (fp32, pre-round)
                bf16_t hv = (bf16_t)av;
                if (col < 128) sqk[(rowb + r) * 136 + col] = hv;
                else           sv[(col - 128) * 40 + rowb + r] = hv;
            }
        }
    }
    __syncthreads();

    int bb = m0 >> 12, l0 = m0 & 4095;
    int t64 = l0 >> 6, stile = (l0 >> 5) & 1, ctop = (l0 >> 4) & 2;
    // Q rows (coalesced 16B)
    {
        int row = tid >> 3, off = (tid & 7) * 8;
        bf16x8 v = *(const bf16x8*)&sqk[row * 136 + off];
        *(bf16x8*)(Qb + (size_t)(m0 + row) * HS + off) = v;
    }
    // K fragment blob: 256 x 16B
    {
        int chk = tid >> 6, ln = tid & 63;
        bf16x8 v = *(const bf16x8*)&sqk[(tid & 31) * 136 + 64 + chk * 16 + ((tid >> 5) & 1) * 8];
        *(bf16x8*)(Kp + (size_t)bb * (L_ * HS) +
                   ((((size_t)t64 * 2 + stile) * 4 + chk) * 64 + ln) * 8) = v;
    }
    // V fragment blob, masked rows zeroed: 256 x 16B
    {
        int dt = tid >> 7, chL = (tid >> 6) & 1, ln = tid & 63;
        int hi2 = (tid >> 5) & 1, d31 = tid & 31;
        bf16x8 v  = *(const bf16x8*)&sv[(dt * 32 + d31) * 40 + chL * 16 + hi2 * 8];
        bf16x8 mm = *(const bf16x8*)(m01p + (size_t)m0 + chL * 16 + hi2 * 8);
        bf16x8 o;
#pragma unroll
        for (int j = 0; j < 8; ++j) o[j] = (bf16_t)((float)v[j] * (float)mm[j]);
        *(bf16x8*)(Vp + (size_t)bb * (L_ * HS) +
                   ((((size_t)t64 * 2 + dt) * 4 + ctop + chL) * 64 + ln) * 8) = o;
    }
}

// ---------------------------------------------------------------------------
// Kernel 3: attention — all-register, single-Q (R8 best form), one-iteration
// K register prefetch: K(t+1) loads issue immediately after the QK MFMAs
// consume K(t); V/m01 issue before QK (covered by QK+exp2+pack).
// nsplit=8, grid 1024 = 4 blocks/CU; VGPR ~70-90, zero LDS/barriers.
// ---------------------------------------------------------------------------
template<int NSPLIT>
__global__ __launch_bounds__(256, 2) void attn_kernel(const bf16_t* __restrict__ Qb,
                                                      const bf16_t* __restrict__ Kp,
                                                      const bf16_t* __restrict__ Vp,
                                                      const bf16_t* __restrict__ m01p,
                                                      const int* __restrict__ flags,
                                                      float* __restrict__ Opart,
                                                      float* __restrict__ lpart,
                                                      void* __restrict__ outv) {
    constexpr int KCH = L_ / NSPLIT;
    constexpr int NHT = KCH / 32;                     // 32-key half-tiles

    int tid = threadIdx.x, wave = tid >> 6, lane = tid & 63;
    int hi = lane >> 5, l31 = lane & 31;
    int grp = blockIdx.x % (B_ * NSPLIT);
    int qt  = blockIdx.x / (B_ * NSPLIT);
    int sp = grp / B_, b = grp % B_;
    int q0 = qt * 128 + wave * 32;
    int hb = sp * NHT;

    const bf16_t* KpB = Kp + (size_t)b * (L_ * HS);
    const bf16_t* VpB = Vp + (size_t)b * (L_ * HS);
    const bf16_t* mB  = m01p + (size_t)b * L_ + sp * KCH;

    // Q as MFMA32 B-frag: B[col=q=l31][k_hs = hi*8+j], 4 hs-chunks. Pre-scaled.
    bf16x8 Qf[4];
    {
        const bf16_t* qp = Qb + (size_t)(b * L_ + q0 + l31) * HS + hi * 8;
#pragma unroll
        for (int c = 0; c < 4; ++c) Qf[c] = *(const bf16x8*)(qp + c * 16);
    }

    f32x16 O0 = {}, O1 = {}, den = {};

    auto loadK = [&](bf16x8* Kf, int t) {
        const bf16_t* kt = KpB + (size_t)(hb + t) * 2048;
#pragma unroll
        for (int c = 0; c < 4; ++c)
            Kf[c] = *(const bf16x8*)(kt + ((size_t)c * 64 + lane) * 8);
    };

    bf16x8 Kfr[4];
    loadK(Kfr, 0);                       // cold start: one exposed latency

    for (int t = 0; t < NHT; ++t) {
        int ht = hb + t;
        int t64 = ht >> 1, stile = ht & 1;
        const bf16_t* vt = VpB + (size_t)t64 * 4096;
        const bf16_t* mt = mB + t * 32;

        // V + m01 for THIS tile, issued before QK: their latency is covered
        // by QK-issue + exp2 + pack (~250 cyc); consumed only at PV.
        bf16x8 V0[2], V1[2], Mf[2];
#pragma unroll
        for (int cc = 0; cc < 2; ++cc) {
            int chk = stile * 2 + cc;
            V0[cc] = *(const bf16x8*)(vt + (size_t)(0 * 4 + chk) * 512 + lane * 8);
            V1[cc] = *(const bf16x8*)(vt + (size_t)(1 * 4 + chk) * 512 + lane * 8);
            Mf[cc] = *(const bf16x8*)(mt + cc * 16 + hi * 8);   // broadcast 16B
        }

        f32x16 S = {};
        __builtin_amdgcn_s_setprio(1);
#pragma unroll
        for (int c = 0; c < 4; ++c)                  // hs chunks of 16
            S = MFMA32(Kfr[c], Qf[c], S, 0, 0, 0);   // S[k][q]: lane q=l31, k=(r&3)+8*(r>>2)+4*hi
        __builtin_amdgcn_s_setprio(0);

        // K prefetch for t+1: issued AFTER the MFMAs that read Kfr (WAR safe,
        // in-order issue); in flight during exp2+pack+PV below — full cover.
        if (t + 1 < NHT) loadK(Kfr, t + 1);

#pragma unroll
        for (int r = 0; r < 16; ++r) S[r] = exp2f(S[r]);   // no bias, no scale

#pragma unroll
        for (int cc = 0; cc < 2; ++cc) {             // 16-key PV chunks
            unsigned w0 = pk_bf16(S[cc * 8 + 0], S[cc * 8 + 1]);
            unsigned w1 = pk_bf16(S[cc * 8 + 2], S[cc * 8 + 3]);
            unsigned w2 = pk_bf16(S[cc * 8 + 4], S[cc * 8 + 5]);
            unsigned w3 = pk_bf16(S[cc * 8 + 6], S[cc * 8 + 7]);
            swap32(w0, w2);                          // both results usable: A-frag k-order
            swap32(w1, w3);
            union { unsigned u[4]; bf16x8 v; } P;
            P.u[0] = w0; P.u[1] = w1; P.u[2] = w2; P.u[3] = w3;
            __builtin_amdgcn_s_setprio(1);
            O0  = MFMA32(P.v, V0[cc], O0, 0, 0, 0);
            O1  = MFMA32(P.v, V1[cc], O1, 0, 0, 0);
            den = MFMA32(P.v, Mf[cc], den, 0, 0, 0); // masked rowsum (denominator)
            __builtin_amdgcn_s_setprio(0);
        }
    }

    // O layout: col = l31 = d (O0: d 0..31, O1: d 32..63); regs = q rows.
    if (NSPLIT == 1) {
        int of32 = flags[1];
#pragma unroll
        for (int r = 0; r < 16; ++r) {
            int qr = (r & 3) + 8 * (r >> 2) + 4 * hi;
            float inv = 1.0f / den[r];
            size_t base = (size_t)(b * L_ + q0 + qr) * HS;
            if (of32) {
                float* op = (float*)outv + base;
                op[l31]      = O0[r] * inv;
                op[32 + l31] = O1[r] * inv;
            } else {
                bf16_t* op = (bf16_t*)outv + base;
                op[l31]      = (bf16_t)(O0[r] * inv);
                op[32 + l31] = (bf16_t)(O1[r] * inv);
            }
        }
    } else {
        float* op = Opart + (size_t)sp * (B_ * L_ * HS) + (size_t)(b * L_ + q0) * HS + l31;
#pragma unroll
        for (int r = 0; r < 16; ++r) {
            int qr = (r & 3) + 8 * (r >> 2) + 4 * hi;
            op[(size_t)qr * HS]      = O0[r];
            op[(size_t)qr * HS + 32] = O1[r];
        }
        if (l31 == 0) {
            float* lp = lpart + (size_t)sp * (B_ * L_) + b * L_ + q0;
#pragma unroll
            for (int r = 0; r < 16; ++r)
                lp[(r & 3) + 8 * (r >> 2) + 4 * hi] = den[r];
        }
    }
}

// ---------------------------------------------------------------------------
// Kernel 4: combine split-K partials, f32x4-vectorized.
// ---------------------------------------------------------------------------
__global__ __launch_bounds__(256) void reduce_kernel(const float* __restrict__ Opart,
                                                     const float* __restrict__ lpart,
                                                     const int* __restrict__ flags,
                                                     void* __restrict__ outv,
                                                     int nsplit) {
    int i4 = (blockIdx.x * 256 + threadIdx.x) * 4;   // over B_*L_*HS
    int row = i4 >> 6;                                // b*L_ + l
    f32x4 acc = {};
    float lsum = 0.f;
    for (int s = 0; s < nsplit; ++s) {
        acc  += *(const f32x4*)&Opart[(size_t)s * (B_ * L_ * HS) + i4];
        lsum += lpart[(size_t)s * (B_ * L_) + row];
    }
    float inv = 1.0f / lsum;
    if (flags[1]) {
        f32x4 r = { acc[0] * inv, acc[1] * inv, acc[2] * inv, acc[3] * inv };
        *(f32x4*)&((float*)outv)[i4] = r;
    } else {
        bf16x4 r;
#pragma unroll
        for (int j = 0; j < 4; ++j) r[j] = (bf16_t)(acc[j] * inv);
        *(bf16x4*)&((bf16_t*)outv)[i4] = r;
    }
}

// ---------------------------------------------------------------------------
extern "C" void kernel_launch(void* const* d_in, const int* in_sizes, int n_in,
                              void* d_out, int out_size, void* d_ws, size_t ws_size,
                              hipStream_t stream) {
    (void)in_sizes; (void)n_in; (void)out_size;
    const void* x    = d_in[0];
    const void* mask = d_in[1];
    const void* W    = d_in[2];

    char* ws = (char*)d_ws;
    bf16_t* Qb    = (bf16_t*)(ws);                              // 2 MB
    bf16_t* Kp    = (bf16_t*)(ws + (2u << 20));                 // 2 MB (fragment blob)
    bf16_t* Vp    = (bf16_t*)(ws + (4u << 20));                 // 2 MB (fragment blob)
    bf16_t* Wtp   = (bf16_t*)(ws + (6u << 20));                 // 384 KB
    int*    flags = (int*)   (ws + (6u << 20) + (512u << 10));  // 4 KB
    bf16_t* m01p  = (bf16_t*)(ws + (6u << 20) + (516u << 10));  // 32 KB
    float*  Opart = (float*) (ws + (7u << 20));                 // nsplit * 4 MB

    auto need = [](int ns) -> size_t {
        return (7u << 20) + (size_t)ns * (B_ * L_ * HS * 4)
                          + (size_t)ns * (B_ * L_ * 4) + 4096;
    };
    int nsplit = (ws_size >= need(8)) ? 8 : (ws_size >= need(4)) ? 4 : 1;
    float* lpart = (float*)(ws + (7u << 20) + (size_t)nsplit * (B_ * L_ * HS * 4));

    pack_w_kernel<<<96, 256, 0, stream>>>(W, (const unsigned char*)mask,
                                          (const unsigned short*)x, Wtp, flags, m01p);
    qkv_gemm_kernel<<<512, 256, 0, stream>>>(x, flags, Wtp, m01p, Qb, Kp, Vp);
    if (nsplit == 8) {
        attn_kernel<8><<<32 * B_ * 8, 256, 0, stream>>>(Qb, Kp, Vp, m01p, flags,
                                                        Opart, lpart, d_out);
        reduce_kernel<<<(B_ * L_ * HS) / 1024, 256, 0, stream>>>(Opart, lpart, flags,
                                                                 d_out, 8);
    } else if (nsplit == 4) {
        attn_kernel<4><<<32 * B_ * 4, 256, 0, stream>>>(Qb, Kp, Vp, m01p, flags,
                                                        Opart, lpart, d_out);
        reduce_kernel<<<(B_ * L_ * HS) / 1024, 256, 0, stream>>>(Opart, lpart, flags,
                                                                 d_out, 4);
    } else {
        attn_kernel<1><<<32 * B_, 256, 0, stream>>>(Qb, Kp, Vp, m01p, flags,
                                                    Opart, lpart, d_out);
    }
}